// Round 2
// baseline (9411.961 us; speedup 1.0000x reference)
//
#include <hip/hip_runtime.h>
#include <hip/hip_bf16.h>
#include <math.h>

// Problem constants (from reference)
#define BB 32768
#define DD 64
#define CC 64
#define HH 1024
#define LL 6
#define SPLIT 32
#define NIN 96
#define EPSV 1e-5f
#define CH 8192              // batch chunk (limits workspace to ~76 MB)

// ---------------------------------------------------------------------------
// Templated fp32 tiled GEMM: C = op(A @ Bm [+ bias])
//  CONCAT_A: A[row, col] = col<32 ? x[row0+row, 2*col+keep_off] : cond[row0+row, col-32]
//  RELU_BIAS: C = relu(acc + bias[col])
//  A and Cc are chunk-local (row 0 == global row row0).
// ---------------------------------------------------------------------------
template<int BM, int BN, int BK, int TM, int TN, bool CONCAT_A, bool RELU_BIAS>
__global__ __launch_bounds__((BM/TM)*(BN/TN))
void gemm_kernel(const float* __restrict__ A,
                 const float* __restrict__ x, const float* __restrict__ cond,
                 int keep_off, int row0,
                 const float* __restrict__ Bm,
                 const float* __restrict__ bias,
                 float* __restrict__ Cc, int N, int K)
{
    constexpr int THREADS = (BM/TM)*(BN/TN);
    __shared__ float As[BK][BM + 4];
    __shared__ float Bs[BK][BN + 4];

    const int t  = threadIdx.x;
    const int bn = blockIdx.x * BN;
    const int bm = blockIdx.y * BM;
    const int tx = t % (BN/TN);
    const int ty = t / (BN/TN);

    float acc[TM][TN];
#pragma unroll
    for (int i = 0; i < TM; ++i)
#pragma unroll
        for (int j = 0; j < TN; ++j) acc[i][j] = 0.f;

    for (int k0 = 0; k0 < K; k0 += BK) {
        // ---- load A tile (BM x BK) into As[k][m] (transposed) ----
        if (!CONCAT_A) {
#pragma unroll
            for (int idx = t * 4; idx < BM * BK; idx += THREADS * 4) {
                int row = idx / BK, kk = idx % BK;
                float4 v = *(const float4*)(A + (size_t)(bm + row) * K + k0 + kk);
                As[kk + 0][row] = v.x;
                As[kk + 1][row] = v.y;
                As[kk + 2][row] = v.z;
                As[kk + 3][row] = v.w;
            }
        } else {
#pragma unroll
            for (int idx = t; idx < BM * BK; idx += THREADS) {
                int row = idx / BK, kk = idx % BK;
                int col = k0 + kk;
                float v;
                if (col < SPLIT) v = x[(size_t)(row0 + bm + row) * DD + 2 * col + keep_off];
                else             v = cond[(size_t)(row0 + bm + row) * CC + (col - SPLIT)];
                As[kk][row] = v;
            }
        }
        // ---- load B tile (BK x BN) ----
#pragma unroll
        for (int idx = t * 4; idx < BK * BN; idx += THREADS * 4) {
            int row = idx / BN, col = idx % BN;
            float4 v = *(const float4*)(Bm + (size_t)(k0 + row) * N + bn + col);
            *(float4*)&Bs[row][col] = v;
        }
        __syncthreads();

#pragma unroll
        for (int kk = 0; kk < BK; ++kk) {
            float ar[TM], br[TN];
#pragma unroll
            for (int i = 0; i < TM; i += 4) {
                float4 v = *(const float4*)&As[kk][ty * TM + i];
                ar[i] = v.x; ar[i+1] = v.y; ar[i+2] = v.z; ar[i+3] = v.w;
            }
#pragma unroll
            for (int j = 0; j < TN; j += 4) {
                float4 v = *(const float4*)&Bs[kk][tx * TN + j];
                br[j] = v.x; br[j+1] = v.y; br[j+2] = v.z; br[j+3] = v.w;
            }
#pragma unroll
            for (int i = 0; i < TM; ++i)
#pragma unroll
                for (int j = 0; j < TN; ++j)
                    acc[i][j] = fmaf(ar[i], br[j], acc[i][j]);
        }
        __syncthreads();
    }

    // ---- epilogue ----
#pragma unroll
    for (int i = 0; i < TM; ++i) {
        int row = bm + ty * TM + i;
#pragma unroll
        for (int j = 0; j < TN; j += 4) {
            int col = bn + tx * TN + j;
            float4 v = { acc[i][j], acc[i][j+1], acc[i][j+2], acc[i][j+3] };
            if (RELU_BIAS) {
                v.x = fmaxf(v.x + bias[col + 0], 0.f);
                v.y = fmaxf(v.y + bias[col + 1], 0.f);
                v.z = fmaxf(v.z + bias[col + 2], 0.f);
                v.w = fmaxf(v.w + bias[col + 3], 0.f);
            }
            *(float4*)(Cc + (size_t)row * N + col) = v;
        }
    }
}

// ---------------------------------------------------------------------------
// Build concatenated [Ws | Wt] weights for all layers: (L, H, 64)
// ---------------------------------------------------------------------------
__global__ void build_wst_kernel(const float* __restrict__ Ws, const float* __restrict__ Wt,
                                 float* __restrict__ Wst)
{
    int idx = blockIdx.x * blockDim.x + threadIdx.x;   // over L*H*64
    int c  = idx & 63;
    int lk = idx >> 6;       // l*H + k
    float v = (c < SPLIT) ? Ws[(size_t)lk * SPLIT + c] : Wt[(size_t)lk * SPLIT + (c - SPLIT)];
    Wst[idx] = v;
}

// ---------------------------------------------------------------------------
// Coupling: x[chg] = x[chg]*exp(tanh(st_s + bs)) + (st_t + bt)
// log_det[row] += sum(log_s); accumulate per-feature sum / sumsq (atomics)
// st is chunk-local (row 0 == global row row0); x/log_det are global.
// ---------------------------------------------------------------------------
__global__ __launch_bounds__(256)
void coupling_kernel(const float* __restrict__ st,
                     const float* __restrict__ bs, const float* __restrict__ bt,
                     float* __restrict__ x, float* __restrict__ log_det,
                     float* __restrict__ stat_sum, float* __restrict__ stat_sumsq,
                     int keep_off, int row0)
{
    const int t = threadIdx.x;
    const int f = t & 63;
    const int g = t >> 6;
    const int r0 = blockIdx.x * 64;          // chunk-local
    const bool is_chg = ((f & 1) != keep_off);
    const int j = f >> 1;

    float bsj = 0.f, btj = 0.f;
    if (is_chg) { bsj = bs[j]; btj = bt[j]; }

    float lsum = 0.f, lsum2 = 0.f;

    for (int i = 0; i < 16; ++i) {
        int crow = r0 + g * 16 + i;          // chunk-local row
        int grow = row0 + crow;              // global row
        float xv = x[(size_t)grow * DD + f];
        float ld = 0.f;
        if (is_chg) {
            float s_raw = st[(size_t)crow * DD + j];
            float t_raw = st[(size_t)crow * DD + SPLIT + j];
            float ls = tanhf(s_raw + bsj);
            float tv = t_raw + btj;
            xv = xv * expf(ls) + tv;
            x[(size_t)grow * DD + f] = xv;
            ld = ls;
        }
        for (int off = 32; off > 0; off >>= 1) ld += __shfl_down(ld, off, 64);
        if (f == 0) log_det[grow] += ld;
        lsum  += xv;
        lsum2 += xv * xv;
    }

    __shared__ float ssum[4][64];
    __shared__ float ssum2[4][64];
    ssum[g][f]  = lsum;
    ssum2[g][f] = lsum2;
    __syncthreads();
    if (t < 64) {
        float a = ssum[0][t] + ssum[1][t] + ssum[2][t] + ssum[3][t];
        float b = ssum2[0][t] + ssum2[1][t] + ssum2[2][t] + ssum2[3][t];
        atomicAdd(stat_sum + t, a);
        atomicAdd(stat_sumsq + t, b);
    }
}

// ---------------------------------------------------------------------------
// BN stats finalize (1 block, 64 threads): scale/shift + c = sum(log|w|)
// ---------------------------------------------------------------------------
__global__ void finalize_kernel(const float* __restrict__ stat_sum, const float* __restrict__ stat_sumsq,
                                const float* __restrict__ bn_w, const float* __restrict__ bn_b,
                                float* __restrict__ scale, float* __restrict__ shift,
                                float* __restrict__ cbuf)
{
    int f = threadIdx.x;  // 64
    const float invB = 1.f / (float)BB;
    float mean = stat_sum[f] * invB;
    float var  = stat_sumsq[f] * invB - mean * mean;
    float inv  = rsqrtf(var + EPSV);
    float w    = bn_w[f];
    float sc   = inv * w;
    scale[f] = sc;
    shift[f] = bn_b[f] - mean * sc;
    float lg = logf(fabsf(w));
    for (int off = 32; off > 0; off >>= 1) lg += __shfl_down(lg, off, 64);
    if (f == 0) cbuf[0] = lg;
}

// ---------------------------------------------------------------------------
// BN normalize: x = x*scale[f] + shift[f]; log_det[row] += c
// ---------------------------------------------------------------------------
__global__ __launch_bounds__(256)
void normalize_kernel(const float* __restrict__ xin, float* __restrict__ xout,
                      const float* __restrict__ scale, const float* __restrict__ shift,
                      const float* __restrict__ cbuf, float* __restrict__ log_det)
{
    int idx = blockIdx.x * blockDim.x + threadIdx.x;     // over B*64/4
    int f0 = (idx & 15) * 4;
    float4 v = ((const float4*)xin)[idx];
    v.x = v.x * scale[f0 + 0] + shift[f0 + 0];
    v.y = v.y * scale[f0 + 1] + shift[f0 + 1];
    v.z = v.z * scale[f0 + 2] + shift[f0 + 2];
    v.w = v.w * scale[f0 + 3] + shift[f0 + 3];
    ((float4*)xout)[idx] = v;
    if ((idx & 15) == 0) log_det[idx >> 4] += cbuf[0];
}

// ---------------------------------------------------------------------------
extern "C" void kernel_launch(void* const* d_in, const int* in_sizes, int n_in,
                              void* d_out, int out_size, void* d_ws, size_t ws_size,
                              hipStream_t stream)
{
    const float* z    = (const float*)d_in[0];
    const float* cond = (const float*)d_in[1];
    const float* W1   = (const float*)d_in[2];
    const float* b1   = (const float*)d_in[3];
    const float* W2   = (const float*)d_in[4];
    const float* b2   = (const float*)d_in[5];
    const float* Ws   = (const float*)d_in[6];
    const float* bs   = (const float*)d_in[7];
    const float* Wt   = (const float*)d_in[8];
    const float* bt   = (const float*)d_in[9];
    const float* bn_w = (const float*)d_in[10];
    const float* bn_b = (const float*)d_in[11];

    float* out_x  = (float*)d_out;
    float* out_ld = out_x + (size_t)BB * DD;

    // workspace layout (floats) — total ~76 MB
    float* ws   = (float*)d_ws;
    float* xbuf = ws;                                  // B*D        (8 MB)
    float* h1   = xbuf + (size_t)BB * DD;              // CH*H       (32 MB)
    float* h2   = h1 + (size_t)CH * HH;                // CH*H       (32 MB)
    float* st   = h2 + (size_t)CH * HH;                // CH*64      (2 MB)
    float* wst  = st + (size_t)CH * DD;                // L*H*64     (1.5 MB)
    float* stat_sum   = wst + (size_t)LL * HH * 64;    // 64
    float* stat_sumsq = stat_sum + 64;                 // 64
    float* scalev     = stat_sumsq + 64;               // 64
    float* shiftv     = scalev + 64;                   // 64
    float* cbuf       = shiftv + 64;                   // 1

    // init: x = z, log_det = 0, build [Ws|Wt]
    hipMemcpyAsync(xbuf, z, (size_t)BB * DD * sizeof(float), hipMemcpyDeviceToDevice, stream);
    hipMemsetAsync(out_ld, 0, (size_t)BB * sizeof(float), stream);
    build_wst_kernel<<<(LL * HH * 64) / 256, 256, 0, stream>>>(Ws, Wt, wst);

    for (int l = 0; l < LL; ++l) {
        const int off = l & 1;   // keep parity: even layers keep even features

        hipMemsetAsync(stat_sum, 0, 2 * 64 * sizeof(float), stream);

        for (int c = 0; c < BB / CH; ++c) {
            const int row0 = c * CH;

            // GEMM1: h1 = relu([x_keep, cond] @ W1[l] + b1[l])   (M=CH, K=96, N=1024)
            gemm_kernel<128,128,8,8,8,true,true><<<dim3(HH/128, CH/128), 256, 0, stream>>>(
                nullptr, xbuf, cond, off, row0,
                W1 + (size_t)l * NIN * HH, b1 + (size_t)l * HH, h1, HH, NIN);

            // GEMM2: h2 = relu(h1 @ W2[l] + b2[l])               (M=CH, K=1024, N=1024)
            gemm_kernel<128,128,8,8,8,false,true><<<dim3(HH/128, CH/128), 256, 0, stream>>>(
                h1, nullptr, nullptr, 0, 0,
                W2 + (size_t)l * HH * HH, b2 + (size_t)l * HH, h2, HH, HH);

            // GEMM3: st = h2 @ [Ws|Wt][l]                        (M=CH, K=1024, N=64)
            gemm_kernel<128,64,8,8,4,false,false><<<dim3(1, CH/128), 256, 0, stream>>>(
                h2, nullptr, nullptr, 0, 0,
                wst + (size_t)l * HH * 64, nullptr, st, 64, HH);

            coupling_kernel<<<CH / 64, 256, 0, stream>>>(
                st, bs + (size_t)l * SPLIT, bt + (size_t)l * SPLIT,
                xbuf, out_ld, stat_sum, stat_sumsq, off, row0);
        }

        finalize_kernel<<<1, 64, 0, stream>>>(
            stat_sum, stat_sumsq, bn_w + (size_t)l * DD, bn_b + (size_t)l * DD,
            scalev, shiftv, cbuf);

        float* xout = (l == LL - 1) ? out_x : xbuf;
        normalize_kernel<<<(BB * DD / 4) / 256, 256, 0, stream>>>(
            xbuf, xout, scalev, shiftv, cbuf, out_ld);
    }
}

// Round 3
// 1499.065 us; speedup vs baseline: 6.2786x; 6.2786x over previous
//
#include <hip/hip_runtime.h>
#include <math.h>

// Problem constants
#define BB 32768
#define DD 64
#define CC 64
#define HH 1024
#define LL 6
#define SPLIT 32
#define NIN 96
#define EPSV 1e-5f

typedef short short8 __attribute__((ext_vector_type(8)));
typedef float f32x4 __attribute__((ext_vector_type(4)));

// fp32 -> bf16 round-to-nearest-even (finite inputs)
__device__ __forceinline__ unsigned short f2bf(float f) {
    union { float f; unsigned int u; } c; c.f = f;
    unsigned int u = c.u + 0x7FFFu + ((c.u >> 16) & 1u);
    return (unsigned short)(u >> 16);
}

// ---------------------------------------------------------------------------
// Transpose + convert: dst[c][r] (bf16, row stride Rpad) = src[r][c] (f32,
// row stride C); zero-fill r >= R. grid (Rpad/32, C/32, L), block 256.
// ---------------------------------------------------------------------------
__global__ void transpose_cvt_kernel(const float* __restrict__ src, unsigned short* __restrict__ dst,
                                     int R, int C, int Rpad,
                                     long long sstride, long long dstride)
{
    __shared__ float tile[32][33];
    const float* s = src + (size_t)blockIdx.z * sstride;
    unsigned short* d = dst + (size_t)blockIdx.z * dstride;
    int r0 = blockIdx.x * 32, c0 = blockIdx.y * 32;
    int tc = threadIdx.x & 31, tr = threadIdx.x >> 5;   // 32 x 8
#pragma unroll
    for (int i = 0; i < 4; ++i) {
        int r = r0 + tr + i * 8;
        tile[tr + i * 8][tc] = (r < R) ? s[(size_t)r * C + c0 + tc] : 0.f;
    }
    __syncthreads();
#pragma unroll
    for (int i = 0; i < 4; ++i) {
        int cc = tr + i * 8;
        d[(size_t)(c0 + cc) * Rpad + r0 + tc] = f2bf(tile[tc][cc]);
    }
}

// ---------------------------------------------------------------------------
// Build GEMM1 input: Ain[r][c] bf16, c<32: x[row0+r][2c+off], c<96: cond,
// c>=96: 0 (K padded to 128). grid = CHv*128/256.
// ---------------------------------------------------------------------------
__global__ __launch_bounds__(256)
void build_ain_kernel(const float* __restrict__ x, const float* __restrict__ cond,
                      unsigned short* __restrict__ Ain, int keep_off, int row0)
{
    int t = blockIdx.x * 256 + threadIdx.x;   // over CHv*128
    int c = t & 127, r = t >> 7;
    int grow = row0 + r;
    float v = 0.f;
    if (c < SPLIT)    v = x[(size_t)grow * DD + 2 * c + keep_off];
    else if (c < NIN) v = cond[(size_t)grow * CC + (c - SPLIT)];
    Ain[t] = f2bf(v);
}

// ---------------------------------------------------------------------------
// bf16 MFMA GEMM:  C = [relu](A @ B^T + bias)
//   A  : [M][K] bf16 row-major (chunk-local)
//   Bt : [N][K] bf16 row-major (i.e. B transposed / N-major)
// Tile BM x BN, BK=64, WAVES = WM*WN (block = WAVES*64 threads).
// LDS staged via global_load_lds (16B) in fragment order: entry (s,i) holds
// a 16-row x 32-k block with lane l owning  [row i*16+(l&15)][k s*32+(l>>4)*8 ..+8].
// OUT_BF16: LDS-transpose epilogue -> coalesced 16B bf16 stores.
// ---------------------------------------------------------------------------
template<int BM, int BN, int MT, int NT, int WM, int WN, bool OUT_BF16, bool RELU_BIAS>
__global__ __launch_bounds__(WM*WN*64)
void mfma_gemm(const unsigned short* __restrict__ A,
               const unsigned short* __restrict__ Bt,
               const float* __restrict__ bias,
               void* __restrict__ Cc,
               int K, int N)
{
    constexpr int WAVES = WM * WN;
    constexpr int AENT = 2 * (BM / 16);
    constexpr int BENT = 2 * (BN / 16);
    constexpr int STAGE_SH = (AENT + BENT) * 512;
    constexpr int EPI_STRIDE = 72;                       // shorts (16B-aligned rows)
    constexpr int EPI_SH = OUT_BF16 ? (WAVES * MT * 16 * EPI_STRIDE) : 0;
    constexpr int LDS_SH = (EPI_SH > STAGE_SH) ? EPI_SH : STAGE_SH;
    __shared__ unsigned short lds[LDS_SH];

    const int t = threadIdx.x;
    const int w = t >> 6, lane = t & 63;
    const int lane16 = lane & 15, quad = lane >> 4;
    const int wm = w / WN, wn = w % WN;
    const int bm = blockIdx.y * BM, bn = blockIdx.x * BN;

    unsigned short* ldsA = lds;
    unsigned short* ldsB = lds + AENT * 512;

    f32x4 acc[MT][NT];
#pragma unroll
    for (int a = 0; a < MT; ++a)
#pragma unroll
        for (int b = 0; b < NT; ++b) acc[a][b] = (f32x4){0.f, 0.f, 0.f, 0.f};

    for (int k0 = 0; k0 < K; k0 += 64) {
        // ---- stage A tile ----
        for (int e = w; e < AENT; e += WAVES) {          // e wave-uniform
            int s = e / (BM / 16), i = e % (BM / 16);
            const unsigned short* g = A + (size_t)(bm + i * 16 + lane16) * K + (k0 + s * 32 + quad * 8);
            __builtin_amdgcn_global_load_lds(
                (const __attribute__((address_space(1))) unsigned int*)g,
                (__attribute__((address_space(3))) unsigned int*)(ldsA + e * 512), 16, 0, 0);
        }
        // ---- stage B tile ----
        for (int e = w; e < BENT; e += WAVES) {
            int s = e / (BN / 16), j = e % (BN / 16);
            const unsigned short* g = Bt + (size_t)(bn + j * 16 + lane16) * K + (k0 + s * 32 + quad * 8);
            __builtin_amdgcn_global_load_lds(
                (const __attribute__((address_space(1))) unsigned int*)g,
                (__attribute__((address_space(3))) unsigned int*)(ldsB + e * 512), 16, 0, 0);
        }
        __syncthreads();

#pragma unroll
        for (int s = 0; s < 2; ++s) {
            short8 af[MT], bfr[NT];
#pragma unroll
            for (int a = 0; a < MT; ++a)
                af[a] = *(const short8*)(ldsA + ((s * (BM / 16) + wm * MT + a) * 64 + lane) * 8);
#pragma unroll
            for (int b = 0; b < NT; ++b)
                bfr[b] = *(const short8*)(ldsB + ((s * (BN / 16) + wn * NT + b) * 64 + lane) * 8);
#pragma unroll
            for (int a = 0; a < MT; ++a)
#pragma unroll
                for (int b = 0; b < NT; ++b)
                    acc[a][b] = __builtin_amdgcn_mfma_f32_16x16x32_bf16(af[a], bfr[b], acc[a][b], 0, 0, 0);
        }
        __syncthreads();
    }

    // ---- epilogue ----
    if (OUT_BF16) {
        // per-wave scratch (disjoint; all waves past final barrier)
        unsigned short* scr = lds + w * (MT * 16 * EPI_STRIDE);
        float bv[NT];
#pragma unroll
        for (int b = 0; b < NT; ++b)
            bv[b] = RELU_BIAS ? bias[bn + wn * NT * 16 + b * 16 + lane16] : 0.f;
#pragma unroll
        for (int a = 0; a < MT; ++a)
#pragma unroll
            for (int b = 0; b < NT; ++b)
#pragma unroll
                for (int r = 0; r < 4; ++r) {
                    float v = acc[a][b][r] + bv[b];
                    if (RELU_BIAS) v = fmaxf(v, 0.f);
                    scr[(a * 16 + quad * 4 + r) * EPI_STRIDE + b * 16 + lane16] = f2bf(v);
                }
        // readback + coalesced store (wave tile MT*16 x NT*16; NT==4 here)
        unsigned short* Co = (unsigned short*)Cc;
#pragma unroll
        for (int p = 0; p < MT * 16 / 8; ++p) {
            int row = p * 8 + (lane >> 3);
            int colc = (lane & 7) * 8;
            short8 v = *(const short8*)(scr + row * EPI_STRIDE + colc);
            *(short8*)(Co + (size_t)(bm + wm * MT * 16 + row) * N + bn + wn * NT * 16 + colc) = v;
        }
    } else {
        float* Co = (float*)Cc;
#pragma unroll
        for (int a = 0; a < MT; ++a)
#pragma unroll
            for (int b = 0; b < NT; ++b)
#pragma unroll
                for (int r = 0; r < 4; ++r) {
                    int row = bm + wm * MT * 16 + a * 16 + quad * 4 + r;
                    int col = bn + wn * NT * 16 + b * 16 + lane16;
                    float v = acc[a][b][r];
                    if (RELU_BIAS) v = fmaxf(v + bias[col], 0.f);
                    Co[(size_t)row * N + col] = v;
                }
    }
}

// ---------------------------------------------------------------------------
// Coupling: x[chg] = x[chg]*exp(tanh(st_s + bs)) + (st_t + bt)
// log_det[row] += sum(log_s); per-feature sum/sumsq accumulated (atomics).
// st chunk-local fp32 [CH][64] (cols 0..31 = s, 32..63 = t).
// ---------------------------------------------------------------------------
__global__ __launch_bounds__(256)
void coupling_kernel(const float* __restrict__ st,
                     const float* __restrict__ bs, const float* __restrict__ bt,
                     float* __restrict__ x, float* __restrict__ log_det,
                     float* __restrict__ stat_sum, float* __restrict__ stat_sumsq,
                     int keep_off, int row0)
{
    const int t = threadIdx.x;
    const int f = t & 63;
    const int g = t >> 6;
    const int r0 = blockIdx.x * 64;          // chunk-local
    const bool is_chg = ((f & 1) != keep_off);
    const int j = f >> 1;

    float bsj = 0.f, btj = 0.f;
    if (is_chg) { bsj = bs[j]; btj = bt[j]; }

    float lsum = 0.f, lsum2 = 0.f;

    for (int i = 0; i < 16; ++i) {
        int crow = r0 + g * 16 + i;
        int grow = row0 + crow;
        float xv = x[(size_t)grow * DD + f];
        float ld = 0.f;
        if (is_chg) {
            float s_raw = st[(size_t)crow * DD + j];
            float t_raw = st[(size_t)crow * DD + SPLIT + j];
            float ls = tanhf(s_raw + bsj);
            float tv = t_raw + btj;
            xv = xv * expf(ls) + tv;
            x[(size_t)grow * DD + f] = xv;
            ld = ls;
        }
        for (int off = 32; off > 0; off >>= 1) ld += __shfl_down(ld, off, 64);
        if (f == 0) log_det[grow] += ld;
        lsum  += xv;
        lsum2 += xv * xv;
    }

    __shared__ float ssum[4][64];
    __shared__ float ssum2[4][64];
    ssum[g][f]  = lsum;
    ssum2[g][f] = lsum2;
    __syncthreads();
    if (t < 64) {
        float a = ssum[0][t] + ssum[1][t] + ssum[2][t] + ssum[3][t];
        float b = ssum2[0][t] + ssum2[1][t] + ssum2[2][t] + ssum2[3][t];
        atomicAdd(stat_sum + t, a);
        atomicAdd(stat_sumsq + t, b);
    }
}

// ---------------------------------------------------------------------------
__global__ void finalize_kernel(const float* __restrict__ stat_sum, const float* __restrict__ stat_sumsq,
                                const float* __restrict__ bn_w, const float* __restrict__ bn_b,
                                float* __restrict__ scale, float* __restrict__ shift,
                                float* __restrict__ cbuf)
{
    int f = threadIdx.x;  // 64
    const float invB = 1.f / (float)BB;
    float mean = stat_sum[f] * invB;
    float var  = stat_sumsq[f] * invB - mean * mean;
    float inv  = rsqrtf(var + EPSV);
    float w    = bn_w[f];
    float sc   = inv * w;
    scale[f] = sc;
    shift[f] = bn_b[f] - mean * sc;
    float lg = logf(fabsf(w));
    for (int off = 32; off > 0; off >>= 1) lg += __shfl_down(lg, off, 64);
    if (f == 0) cbuf[0] = lg;
}

// ---------------------------------------------------------------------------
__global__ __launch_bounds__(256)
void normalize_kernel(const float* __restrict__ xin, float* __restrict__ xout,
                      const float* __restrict__ scale, const float* __restrict__ shift,
                      const float* __restrict__ cbuf, float* __restrict__ log_det)
{
    int idx = blockIdx.x * blockDim.x + threadIdx.x;     // over B*64/4
    int f0 = (idx & 15) * 4;
    float4 v = ((const float4*)xin)[idx];
    v.x = v.x * scale[f0 + 0] + shift[f0 + 0];
    v.y = v.y * scale[f0 + 1] + shift[f0 + 1];
    v.z = v.z * scale[f0 + 2] + shift[f0 + 2];
    v.w = v.w * scale[f0 + 3] + shift[f0 + 3];
    ((float4*)xout)[idx] = v;
    if ((idx & 15) == 0) log_det[idx >> 4] += cbuf[0];
}

// ---------------------------------------------------------------------------
extern "C" void kernel_launch(void* const* d_in, const int* in_sizes, int n_in,
                              void* d_out, int out_size, void* d_ws, size_t ws_size,
                              hipStream_t stream)
{
    const float* z    = (const float*)d_in[0];
    const float* cond = (const float*)d_in[1];
    const float* W1   = (const float*)d_in[2];
    const float* b1   = (const float*)d_in[3];
    const float* W2   = (const float*)d_in[4];
    const float* b2   = (const float*)d_in[5];
    const float* Ws   = (const float*)d_in[6];
    const float* bs   = (const float*)d_in[7];
    const float* Wt   = (const float*)d_in[8];
    const float* bt   = (const float*)d_in[9];
    const float* bn_w = (const float*)d_in[10];
    const float* bn_b = (const float*)d_in[11];

    float* out_x  = (float*)d_out;
    float* out_ld = out_x + (size_t)BB * DD;

    // ---- workspace layout (fixed part ~23.4 MB) ----
    char* p = (char*)d_ws;
    size_t used = 0;
    auto alloc = [&](size_t bytes) { void* q = p + used; used += (bytes + 255) & ~(size_t)255; return q; };

    float*          xbuf = (float*)alloc((size_t)BB * DD * 4);
    unsigned short* w1t  = (unsigned short*)alloc((size_t)LL * HH * 128 * 2);   // [L][1024][128]
    unsigned short* w2t  = (unsigned short*)alloc((size_t)LL * HH * HH * 2);    // [L][1024][1024]
    unsigned short* wstt = (unsigned short*)alloc((size_t)LL * 64 * HH * 2);    // [L][64][1024]
    float* stat_sum   = (float*)alloc(64 * 4);
    float* stat_sumsq = (float*)alloc(64 * 4);
    float* scalev     = (float*)alloc(64 * 4);
    float* shiftv     = (float*)alloc(64 * 4);
    float* cbuf       = (float*)alloc(64 * 4);

    // adaptive chunk: per-CH bytes = CH*(256 + 2048 + 2048 + 256) = CH*4608
    int CHv = 32768;
    while (CHv > 8192 && used + (size_t)CHv * 4608 + 4096 > ws_size) CHv >>= 1;

    unsigned short* Ain = (unsigned short*)alloc((size_t)CHv * 128 * 2);
    unsigned short* h1  = (unsigned short*)alloc((size_t)CHv * HH * 2);
    unsigned short* h2  = (unsigned short*)alloc((size_t)CHv * HH * 2);
    float*          st  = (float*)alloc((size_t)CHv * 64 * 4);

    // ---- init ----
    hipMemcpyAsync(xbuf, z, (size_t)BB * DD * sizeof(float), hipMemcpyDeviceToDevice, stream);
    hipMemsetAsync(out_ld, 0, (size_t)BB * sizeof(float), stream);

    // weights -> bf16, N-major (B^T), K padded where needed
    transpose_cvt_kernel<<<dim3(128/32, HH/32, LL), 256, 0, stream>>>(
        W1, w1t, NIN, HH, 128, (long long)NIN * HH, (long long)HH * 128);
    transpose_cvt_kernel<<<dim3(HH/32, HH/32, LL), 256, 0, stream>>>(
        W2, w2t, HH, HH, HH, (long long)HH * HH, (long long)HH * HH);
    transpose_cvt_kernel<<<dim3(HH/32, SPLIT/32, LL), 256, 0, stream>>>(
        Ws, wstt, HH, SPLIT, HH, (long long)HH * SPLIT, (long long)64 * HH);
    transpose_cvt_kernel<<<dim3(HH/32, SPLIT/32, LL), 256, 0, stream>>>(
        Wt, wstt + (size_t)SPLIT * HH, HH, SPLIT, HH, (long long)HH * SPLIT, (long long)64 * HH);

    for (int l = 0; l < LL; ++l) {
        const int off = l & 1;
        hipMemsetAsync(stat_sum, 0, 2 * 64 * sizeof(float), stream);

        for (int c = 0; c < BB / CHv; ++c) {
            const int row0 = c * CHv;

            build_ain_kernel<<<CHv * 128 / 256, 256, 0, stream>>>(xbuf, cond, Ain, off, row0);

            // GEMM1: h1 = relu(Ain @ W1t^T + b1)   M=CHv, K=128(pad), N=1024
            mfma_gemm<128,128,4,4,2,2,true,true><<<dim3(HH/128, CHv/128), 256, 0, stream>>>(
                Ain, w1t + (size_t)l * HH * 128, b1 + (size_t)l * HH, h1, 128, HH);

            // GEMM2: h2 = relu(h1 @ W2t^T + b2)    M=CHv, K=1024, N=1024
            mfma_gemm<128,128,4,4,2,2,true,true><<<dim3(HH/128, CHv/128), 256, 0, stream>>>(
                h1, w2t + (size_t)l * HH * HH, b2 + (size_t)l * HH, h2, HH, HH);

            // GEMM3: st = h2 @ Wstt^T (fp32 out)   M=CHv, K=1024, N=64
            mfma_gemm<128,64,4,2,2,2,false,false><<<dim3(1, CHv/128), 256, 0, stream>>>(
                h2, wstt + (size_t)l * 64 * HH, nullptr, st, HH, 64);

            coupling_kernel<<<CHv / 64, 256, 0, stream>>>(
                st, bs + (size_t)l * SPLIT, bt + (size_t)l * SPLIT,
                xbuf, out_ld, stat_sum, stat_sumsq, off, row0);
        }

        finalize_kernel<<<1, 64, 0, stream>>>(
            stat_sum, stat_sumsq, bn_w + (size_t)l * DD, bn_b + (size_t)l * DD,
            scalev, shiftv, cbuf);

        float* xout = (l == LL - 1) ? out_x : xbuf;
        normalize_kernel<<<(BB * DD / 4) / 256, 256, 0, stream>>>(
            xbuf, xout, scalev, shiftv, cbuf, out_ld);
    }
}

// Round 4
// 1397.632 us; speedup vs baseline: 6.7342x; 1.0726x over previous
//
#include <hip/hip_runtime.h>
#include <math.h>

// Problem constants
#define BB 32768
#define DD 64
#define CC 64
#define HH 1024
#define LL 6
#define SPLIT 32
#define NIN 96
#define EPSV 1e-5f

typedef short short8 __attribute__((ext_vector_type(8)));
typedef float f32x4 __attribute__((ext_vector_type(4)));

// fp32 -> bf16 round-to-nearest-even (finite inputs)
__device__ __forceinline__ unsigned short f2bf(float f) {
    union { float f; unsigned int u; } c; c.f = f;
    unsigned int u = c.u + 0x7FFFu + ((c.u >> 16) & 1u);
    return (unsigned short)(u >> 16);
}

// ---------------------------------------------------------------------------
// Transpose + convert: dst[c][r] (bf16, row stride Rpad) = src[r][c] (f32,
// row stride C); zero-fill r >= R. grid (Rpad/32, C/32, L), block 256.
// ---------------------------------------------------------------------------
__global__ void transpose_cvt_kernel(const float* __restrict__ src, unsigned short* __restrict__ dst,
                                     int R, int C, int Rpad,
                                     long long sstride, long long dstride)
{
    __shared__ float tile[32][33];
    const float* s = src + (size_t)blockIdx.z * sstride;
    unsigned short* d = dst + (size_t)blockIdx.z * dstride;
    int r0 = blockIdx.x * 32, c0 = blockIdx.y * 32;
    int tc = threadIdx.x & 31, tr = threadIdx.x >> 5;   // 32 x 8
#pragma unroll
    for (int i = 0; i < 4; ++i) {
        int r = r0 + tr + i * 8;
        tile[tr + i * 8][tc] = (r < R) ? s[(size_t)r * C + c0 + tc] : 0.f;
    }
    __syncthreads();
#pragma unroll
    for (int i = 0; i < 4; ++i) {
        int cc = tr + i * 8;
        d[(size_t)(c0 + cc) * Rpad + r0 + tc] = f2bf(tile[tc][cc]);
    }
}

// ---------------------------------------------------------------------------
// One-time: fill Ain cond columns (32..95) + zero pad (96..127), all BB rows.
// ---------------------------------------------------------------------------
__global__ __launch_bounds__(256)
void init_ain_cond_kernel(const float* __restrict__ cond, unsigned short* __restrict__ Ain)
{
    int t = blockIdx.x * 256 + threadIdx.x;   // over BB*96
    int c = t % 96, r = t / 96;
    Ain[(size_t)r * 128 + 32 + c] = (c < CC) ? f2bf(cond[(size_t)r * CC + c]) : (unsigned short)0;
}

// One-time (layer 0): fill Ain keep columns (0..31) from x.
__global__ __launch_bounds__(256)
void build_keep_kernel(const float* __restrict__ x, unsigned short* __restrict__ Ain, int keep_off)
{
    int t = blockIdx.x * 256 + threadIdx.x;   // over BB*32
    int c = t & 31, r = t >> 5;
    Ain[(size_t)r * 128 + c] = f2bf(x[(size_t)r * DD + 2 * c + keep_off]);
}

// Fallback (chunked path): build full Ain rows for one chunk.
__global__ __launch_bounds__(256)
void build_ain_kernel(const float* __restrict__ x, const float* __restrict__ cond,
                      unsigned short* __restrict__ Ain, int keep_off, int row0)
{
    int t = blockIdx.x * 256 + threadIdx.x;   // over CHv*128
    int c = t & 127, r = t >> 7;
    int grow = row0 + r;
    float v = 0.f;
    if (c < SPLIT)    v = x[(size_t)grow * DD + 2 * c + keep_off];
    else if (c < NIN) v = cond[(size_t)grow * CC + (c - SPLIT)];
    Ain[t] = f2bf(v);
}

// ---------------------------------------------------------------------------
// bf16 MFMA GEMM:  C = [relu](A @ B^T + bias)
// 1D grid (nbx * nby blocks) with XCD-aware swizzle: N-block index sweeps
// fastest within an XCD so blocks sharing an A row-block run on one XCD.
// ---------------------------------------------------------------------------
template<int BM, int BN, int MT, int NT, int WM, int WN, bool OUT_BF16, bool RELU_BIAS>
__global__ __launch_bounds__(WM*WN*64)
void mfma_gemm(const unsigned short* __restrict__ A,
               const unsigned short* __restrict__ Bt,
               const float* __restrict__ bias,
               void* __restrict__ Cc,
               int K, int N, int nbx)
{
    constexpr int WAVES = WM * WN;
    constexpr int AENT = 2 * (BM / 16);
    constexpr int BENT = 2 * (BN / 16);
    constexpr int STAGE_SH = (AENT + BENT) * 512;
    constexpr int EPI_STRIDE = 72;
    constexpr int EPI_SH = OUT_BF16 ? (WAVES * MT * 16 * EPI_STRIDE) : 0;
    constexpr int LDS_SH = (EPI_SH > STAGE_SH) ? EPI_SH : STAGE_SH;
    __shared__ unsigned short lds[LDS_SH];

    const int t = threadIdx.x;
    const int w = t >> 6, lane = t & 63;
    const int lane16 = lane & 15, quad = lane >> 4;
    const int wm = w / WN, wn = w % WN;

    // ---- XCD swizzle ----
    int id = blockIdx.x;
    int nby = gridDim.x / nbx;
    int bx, by;
    if ((nby & 7) == 0) {
        int xcd = id & 7, slot = id >> 3;
        int q = slot / nbx;
        by = xcd * (nby >> 3) + q;
        bx = slot - q * nbx;
    } else { bx = id % nbx; by = id / nbx; }
    const int bm = by * BM, bn = bx * BN;

    unsigned short* ldsA = lds;
    unsigned short* ldsB = lds + AENT * 512;

    f32x4 acc[MT][NT];
#pragma unroll
    for (int a = 0; a < MT; ++a)
#pragma unroll
        for (int b = 0; b < NT; ++b) acc[a][b] = (f32x4){0.f, 0.f, 0.f, 0.f};

    for (int k0 = 0; k0 < K; k0 += 64) {
        for (int e = w; e < AENT; e += WAVES) {
            int s = e / (BM / 16), i = e % (BM / 16);
            const unsigned short* g = A + (size_t)(bm + i * 16 + lane16) * K + (k0 + s * 32 + quad * 8);
            __builtin_amdgcn_global_load_lds(
                (const __attribute__((address_space(1))) unsigned int*)g,
                (__attribute__((address_space(3))) unsigned int*)(ldsA + e * 512), 16, 0, 0);
        }
        for (int e = w; e < BENT; e += WAVES) {
            int s = e / (BN / 16), j = e % (BN / 16);
            const unsigned short* g = Bt + (size_t)(bn + j * 16 + lane16) * K + (k0 + s * 32 + quad * 8);
            __builtin_amdgcn_global_load_lds(
                (const __attribute__((address_space(1))) unsigned int*)g,
                (__attribute__((address_space(3))) unsigned int*)(ldsB + e * 512), 16, 0, 0);
        }
        __syncthreads();

#pragma unroll
        for (int s = 0; s < 2; ++s) {
            short8 af[MT], bfr[NT];
#pragma unroll
            for (int a = 0; a < MT; ++a)
                af[a] = *(const short8*)(ldsA + ((s * (BM / 16) + wm * MT + a) * 64 + lane) * 8);
#pragma unroll
            for (int b = 0; b < NT; ++b)
                bfr[b] = *(const short8*)(ldsB + ((s * (BN / 16) + wn * NT + b) * 64 + lane) * 8);
#pragma unroll
            for (int a = 0; a < MT; ++a)
#pragma unroll
                for (int b = 0; b < NT; ++b)
                    acc[a][b] = __builtin_amdgcn_mfma_f32_16x16x32_bf16(af[a], bfr[b], acc[a][b], 0, 0, 0);
        }
        __syncthreads();
    }

    // ---- epilogue ----
    if (OUT_BF16) {
        unsigned short* scr = lds + w * (MT * 16 * EPI_STRIDE);
        float bv[NT];
#pragma unroll
        for (int b = 0; b < NT; ++b)
            bv[b] = RELU_BIAS ? bias[bn + wn * NT * 16 + b * 16 + lane16] : 0.f;
#pragma unroll
        for (int a = 0; a < MT; ++a)
#pragma unroll
            for (int b = 0; b < NT; ++b)
#pragma unroll
                for (int r = 0; r < 4; ++r) {
                    float v = acc[a][b][r] + bv[b];
                    if (RELU_BIAS) v = fmaxf(v, 0.f);
                    scr[(a * 16 + quad * 4 + r) * EPI_STRIDE + b * 16 + lane16] = f2bf(v);
                }
        unsigned short* Co = (unsigned short*)Cc;
#pragma unroll
        for (int p = 0; p < MT * 16 / 8; ++p) {
            int row = p * 8 + (lane >> 3);
            int colc = (lane & 7) * 8;
            short8 v = *(const short8*)(scr + row * EPI_STRIDE + colc);
            *(short8*)(Co + (size_t)(bm + wm * MT * 16 + row) * N + bn + wn * NT * 16 + colc) = v;
        }
    } else {
        float* Co = (float*)Cc;
#pragma unroll
        for (int a = 0; a < MT; ++a)
#pragma unroll
            for (int b = 0; b < NT; ++b)
#pragma unroll
                for (int r = 0; r < 4; ++r) {
                    int row = bm + wm * MT * 16 + a * 16 + quad * 4 + r;
                    int col = bn + wn * NT * 16 + b * 16 + lane16;
                    float v = acc[a][b][r];
                    if (RELU_BIAS) v = fmaxf(v + bias[col], 0.f);
                    Co[(size_t)row * N + col] = v;
                }
    }
}

// ---------------------------------------------------------------------------
// Fused GEMM3 + coupling. Block = 128 rows, full N=64. 4 waves (2x2),
// MT=4, NT=2. st tile lives in LDS (stride 66: 2-way conflicts only).
// Epilogue: x[chg] = x[chg]*exp(tanh(s+bs)) + (t+bt); log_det; BN stats.
// ---------------------------------------------------------------------------
__global__ __launch_bounds__(256)
void gemm3_coupling(const unsigned short* __restrict__ A,   // h2 [CH][1024]
                    const unsigned short* __restrict__ Bt,  // wst [64][1024]
                    const float* __restrict__ bs, const float* __restrict__ bt,
                    float* __restrict__ x, float* __restrict__ log_det,
                    float* __restrict__ stat_sum, float* __restrict__ stat_sumsq,
                    int keep_off, int row0)
{
    constexpr int K = HH;
    constexpr int ST_STRIDE = 66;
    __shared__ float sst[128 * ST_STRIDE];            // 33792 B (aliased for staging)
    __shared__ float ssum[4][64], ssum2[4][64];
    unsigned short* lds = (unsigned short*)sst;

    const int t = threadIdx.x;
    const int w = t >> 6, lane = t & 63;
    const int lane16 = lane & 15, quad = lane >> 4;
    const int wm = w >> 1, wn = w & 1;
    const int bm = blockIdx.x * 128;

    unsigned short* ldsA = lds;              // 16 entries * 512
    unsigned short* ldsB = lds + 16 * 512;   // 8 entries * 512

    f32x4 acc[4][2];
#pragma unroll
    for (int a = 0; a < 4; ++a)
#pragma unroll
        for (int b = 0; b < 2; ++b) acc[a][b] = (f32x4){0.f, 0.f, 0.f, 0.f};

    for (int k0 = 0; k0 < K; k0 += 64) {
        for (int e = w; e < 16; e += 4) {
            int s = e >> 3, i = e & 7;
            const unsigned short* g = A + (size_t)(bm + i * 16 + lane16) * K + (k0 + s * 32 + quad * 8);
            __builtin_amdgcn_global_load_lds(
                (const __attribute__((address_space(1))) unsigned int*)g,
                (__attribute__((address_space(3))) unsigned int*)(ldsA + e * 512), 16, 0, 0);
        }
        for (int e = w; e < 8; e += 4) {
            int s = e >> 2, j = e & 3;
            const unsigned short* g = Bt + (size_t)(j * 16 + lane16) * K + (k0 + s * 32 + quad * 8);
            __builtin_amdgcn_global_load_lds(
                (const __attribute__((address_space(1))) unsigned int*)g,
                (__attribute__((address_space(3))) unsigned int*)(ldsB + e * 512), 16, 0, 0);
        }
        __syncthreads();
#pragma unroll
        for (int s = 0; s < 2; ++s) {
            short8 af[4], bfr[2];
#pragma unroll
            for (int a = 0; a < 4; ++a)
                af[a] = *(const short8*)(ldsA + ((s * 8 + wm * 4 + a) * 64 + lane) * 8);
#pragma unroll
            for (int b = 0; b < 2; ++b)
                bfr[b] = *(const short8*)(ldsB + ((s * 4 + wn * 2 + b) * 64 + lane) * 8);
#pragma unroll
            for (int a = 0; a < 4; ++a)
#pragma unroll
                for (int b = 0; b < 2; ++b)
                    acc[a][b] = __builtin_amdgcn_mfma_f32_16x16x32_bf16(af[a], bfr[b], acc[a][b], 0, 0, 0);
        }
        __syncthreads();
    }

    // scatter acc -> LDS st tile
#pragma unroll
    for (int a = 0; a < 4; ++a)
#pragma unroll
        for (int b = 0; b < 2; ++b)
#pragma unroll
            for (int r = 0; r < 4; ++r) {
                int row = wm * 64 + a * 16 + quad * 4 + r;
                int col = wn * 32 + b * 16 + lane16;
                sst[row * ST_STRIDE + col] = acc[a][b][r];
            }
    __syncthreads();

    // coupling: wave w -> rows [w*32, w*32+32), lane = feature f
    const int f = lane;
    const bool is_chg = ((f & 1) != keep_off);
    const int j = f >> 1;
    float bsj = 0.f, btj = 0.f;
    if (is_chg) { bsj = bs[j]; btj = bt[j]; }

    float lsum = 0.f, lsum2 = 0.f;
    for (int i = 0; i < 32; ++i) {
        int crow = w * 32 + i;
        int grow = row0 + bm + crow;
        float xv = x[(size_t)grow * DD + f];
        float ld = 0.f;
        if (is_chg) {
            float s_raw = sst[crow * ST_STRIDE + j];
            float t_raw = sst[crow * ST_STRIDE + SPLIT + j];
            float ls = tanhf(s_raw + bsj);
            float tv = t_raw + btj;
            xv = xv * expf(ls) + tv;
            x[(size_t)grow * DD + f] = xv;
            ld = ls;
        }
        for (int off = 32; off > 0; off >>= 1) ld += __shfl_down(ld, off, 64);
        if (f == 0) log_det[grow] += ld;
        lsum  += xv;
        lsum2 += xv * xv;
    }

    ssum[w][f]  = lsum;
    ssum2[w][f] = lsum2;
    __syncthreads();
    if (t < 64) {
        float a = ssum[0][t] + ssum[1][t] + ssum[2][t] + ssum[3][t];
        float b = ssum2[0][t] + ssum2[1][t] + ssum2[2][t] + ssum2[3][t];
        atomicAdd(stat_sum + t, a);
        atomicAdd(stat_sumsq + t, b);
    }
}

// ---------------------------------------------------------------------------
__global__ void finalize_kernel(const float* __restrict__ stat_sum, const float* __restrict__ stat_sumsq,
                                const float* __restrict__ bn_w, const float* __restrict__ bn_b,
                                float* __restrict__ scale, float* __restrict__ shift,
                                float* __restrict__ cbuf)
{
    int f = threadIdx.x;  // 64
    const float invB = 1.f / (float)BB;
    float mean = stat_sum[f] * invB;
    float var  = stat_sumsq[f] * invB - mean * mean;
    float inv  = rsqrtf(var + EPSV);
    float w    = bn_w[f];
    float sc   = inv * w;
    scale[f] = sc;
    shift[f] = bn_b[f] - mean * sc;
    float lg = logf(fabsf(w));
    for (int off = 32; off > 0; off >>= 1) lg += __shfl_down(lg, off, 64);
    if (f == 0) cbuf[0] = lg;
}

// ---------------------------------------------------------------------------
// BN normalize; optionally also writes bf16 keep-columns of next layer's Ain.
// ---------------------------------------------------------------------------
__global__ __launch_bounds__(256)
void normalize_kernel(const float* __restrict__ xin, float* __restrict__ xout,
                      const float* __restrict__ scale, const float* __restrict__ shift,
                      const float* __restrict__ cbuf, float* __restrict__ log_det,
                      unsigned short* __restrict__ Ain, int off_next)
{
    int idx = blockIdx.x * blockDim.x + threadIdx.x;     // over B*64/4
    int f0 = (idx & 15) * 4;
    int row = idx >> 4;
    float4 v = ((const float4*)xin)[idx];
    v.x = v.x * scale[f0 + 0] + shift[f0 + 0];
    v.y = v.y * scale[f0 + 1] + shift[f0 + 1];
    v.z = v.z * scale[f0 + 2] + shift[f0 + 2];
    v.w = v.w * scale[f0 + 3] + shift[f0 + 3];
    ((float4*)xout)[idx] = v;
    if ((idx & 15) == 0) log_det[row] += cbuf[0];
    if (Ain) {
        float a0 = off_next ? v.y : v.x;
        float a1 = off_next ? v.w : v.z;
        ushort2 u; u.x = f2bf(a0); u.y = f2bf(a1);
        *(ushort2*)(Ain + (size_t)row * 128 + (f0 >> 1)) = u;
    }
}

// ---------------------------------------------------------------------------
extern "C" void kernel_launch(void* const* d_in, const int* in_sizes, int n_in,
                              void* d_out, int out_size, void* d_ws, size_t ws_size,
                              hipStream_t stream)
{
    const float* z    = (const float*)d_in[0];
    const float* cond = (const float*)d_in[1];
    const float* W1   = (const float*)d_in[2];
    const float* b1   = (const float*)d_in[3];
    const float* W2   = (const float*)d_in[4];
    const float* b2   = (const float*)d_in[5];
    const float* Ws   = (const float*)d_in[6];
    const float* bs   = (const float*)d_in[7];
    const float* Wt   = (const float*)d_in[8];
    const float* bt   = (const float*)d_in[9];
    const float* bn_w = (const float*)d_in[10];
    const float* bn_b = (const float*)d_in[11];

    float* out_x  = (float*)d_out;
    float* out_ld = out_x + (size_t)BB * DD;

    // ---- workspace layout ----
    char* p = (char*)d_ws;
    size_t used = 0;
    auto alloc = [&](size_t bytes) { void* q = p + used; used += (bytes + 255) & ~(size_t)255; return q; };

    float*          xbuf = (float*)alloc((size_t)BB * DD * 4);
    unsigned short* w1t  = (unsigned short*)alloc((size_t)LL * HH * 128 * 2);
    unsigned short* w2t  = (unsigned short*)alloc((size_t)LL * HH * HH * 2);
    unsigned short* wstt = (unsigned short*)alloc((size_t)LL * 64 * HH * 2);
    float* stat_sum   = (float*)alloc(64 * 4);
    float* stat_sumsq = (float*)alloc(64 * 4);
    float* scalev     = (float*)alloc(64 * 4);
    float* shiftv     = (float*)alloc(64 * 4);
    float* cbuf       = (float*)alloc(64 * 4);

    // per-chunk bytes: Ain 256 + h1 2048 + h2 2048 = 4352 B/row
    int CHv = BB;
    while (CHv > 8192 && used + (size_t)CHv * 4352 + 4096 > ws_size) CHv >>= 1;
    const bool fused = (CHv == BB);

    unsigned short* Ain = (unsigned short*)alloc((size_t)CHv * 128 * 2);
    unsigned short* h1  = (unsigned short*)alloc((size_t)CHv * HH * 2);
    unsigned short* h2  = (unsigned short*)alloc((size_t)CHv * HH * 2);

    // ---- init ----
    hipMemcpyAsync(xbuf, z, (size_t)BB * DD * sizeof(float), hipMemcpyDeviceToDevice, stream);
    hipMemsetAsync(out_ld, 0, (size_t)BB * sizeof(float), stream);

    transpose_cvt_kernel<<<dim3(128/32, HH/32, LL), 256, 0, stream>>>(
        W1, w1t, NIN, HH, 128, (long long)NIN * HH, (long long)HH * 128);
    transpose_cvt_kernel<<<dim3(HH/32, HH/32, LL), 256, 0, stream>>>(
        W2, w2t, HH, HH, HH, (long long)HH * HH, (long long)HH * HH);
    transpose_cvt_kernel<<<dim3(HH/32, SPLIT/32, LL), 256, 0, stream>>>(
        Ws, wstt, HH, SPLIT, HH, (long long)HH * SPLIT, (long long)64 * HH);
    transpose_cvt_kernel<<<dim3(HH/32, SPLIT/32, LL), 256, 0, stream>>>(
        Wt, wstt + (size_t)SPLIT * HH, HH, SPLIT, HH, (long long)HH * SPLIT, (long long)64 * HH);

    if (fused) {
        init_ain_cond_kernel<<<BB * 96 / 256, 256, 0, stream>>>(cond, Ain);
        build_keep_kernel<<<BB * 32 / 256, 256, 0, stream>>>(xbuf, Ain, 0);
    }

    for (int l = 0; l < LL; ++l) {
        const int off = l & 1;
        hipMemsetAsync(stat_sum, 0, 2 * 64 * sizeof(float), stream);

        for (int c = 0; c < BB / CHv; ++c) {
            const int row0 = c * CHv;

            if (!fused)
                build_ain_kernel<<<CHv * 128 / 256, 256, 0, stream>>>(xbuf, cond, Ain, off, row0);

            // GEMM1: h1 = relu(Ain @ W1t^T + b1)   M=CHv, K=128(pad), N=1024
            mfma_gemm<128,128,4,4,2,2,true,true><<<(HH/128) * (CHv/128), 256, 0, stream>>>(
                Ain, w1t + (size_t)l * HH * 128, b1 + (size_t)l * HH, h1, 128, HH, HH/128);

            // GEMM2: h2 = relu(h1 @ W2t^T + b2)    M=CHv, K=1024, N=1024
            mfma_gemm<128,128,4,4,2,2,true,true><<<(HH/128) * (CHv/128), 256, 0, stream>>>(
                h1, w2t + (size_t)l * HH * HH, b2 + (size_t)l * HH, h2, HH, HH, HH/128);

            // GEMM3 + coupling fused
            gemm3_coupling<<<CHv/128, 256, 0, stream>>>(
                h2, wstt + (size_t)l * 64 * HH,
                bs + (size_t)l * SPLIT, bt + (size_t)l * SPLIT,
                xbuf, out_ld, stat_sum, stat_sumsq, off, row0);
        }

        finalize_kernel<<<1, 64, 0, stream>>>(
            stat_sum, stat_sumsq, bn_w + (size_t)l * DD, bn_b + (size_t)l * DD,
            scalev, shiftv, cbuf);

        float* xout = (l == LL - 1) ? out_x : xbuf;
        unsigned short* ain_next = (fused && l < LL - 1) ? Ain : nullptr;
        normalize_kernel<<<(BB * DD / 4) / 256, 256, 0, stream>>>(
            xbuf, xout, scalev, shiftv, cbuf, out_ld, ain_next, (l + 1) & 1);
    }
}

// Round 5
// 1298.976 us; speedup vs baseline: 7.2457x; 1.0759x over previous
//
#include <hip/hip_runtime.h>
#include <math.h>

// Problem constants
#define BB 32768
#define DD 64
#define CC 64
#define HH 1024
#define LL 6
#define SPLIT 32
#define NIN 96
#define EPSV 1e-5f

typedef short short8 __attribute__((ext_vector_type(8)));
typedef float f32x4 __attribute__((ext_vector_type(4)));

// fp32 -> bf16 round-to-nearest-even (finite inputs)
__device__ __forceinline__ unsigned short f2bf(float f) {
    union { float f; unsigned int u; } c; c.f = f;
    unsigned int u = c.u + 0x7FFFu + ((c.u >> 16) & 1u);
    return (unsigned short)(u >> 16);
}

// ---------------------------------------------------------------------------
// Transpose + convert: dst[c][r] (bf16, row stride Rpad) = src[r][c] (f32)
// ---------------------------------------------------------------------------
__global__ void transpose_cvt_kernel(const float* __restrict__ src, unsigned short* __restrict__ dst,
                                     int R, int C, int Rpad,
                                     long long sstride, long long dstride)
{
    __shared__ float tile[32][33];
    const float* s = src + (size_t)blockIdx.z * sstride;
    unsigned short* d = dst + (size_t)blockIdx.z * dstride;
    int r0 = blockIdx.x * 32, c0 = blockIdx.y * 32;
    int tc = threadIdx.x & 31, tr = threadIdx.x >> 5;   // 32 x 8
#pragma unroll
    for (int i = 0; i < 4; ++i) {
        int r = r0 + tr + i * 8;
        tile[tr + i * 8][tc] = (r < R) ? s[(size_t)r * C + c0 + tc] : 0.f;
    }
    __syncthreads();
#pragma unroll
    for (int i = 0; i < 4; ++i) {
        int cc = tr + i * 8;
        d[(size_t)(c0 + cc) * Rpad + r0 + tc] = f2bf(tile[tc][cc]);
    }
}

// ---------------------------------------------------------------------------
// One-time: fill Ain cond columns (32..95) + zero pad (96..127), all BB rows.
// ---------------------------------------------------------------------------
__global__ __launch_bounds__(256)
void init_ain_cond_kernel(const float* __restrict__ cond, unsigned short* __restrict__ Ain)
{
    int t = blockIdx.x * 256 + threadIdx.x;   // over BB*96
    int c = t % 96, r = t / 96;
    Ain[(size_t)r * 128 + 32 + c] = (c < CC) ? f2bf(cond[(size_t)r * CC + c]) : (unsigned short)0;
}

// One-time (layer 0): fill Ain keep columns (0..31) from x.
__global__ __launch_bounds__(256)
void build_keep_kernel(const float* __restrict__ x, unsigned short* __restrict__ Ain, int keep_off)
{
    int t = blockIdx.x * 256 + threadIdx.x;   // over BB*32
    int c = t & 31, r = t >> 5;
    Ain[(size_t)r * 128 + c] = f2bf(x[(size_t)r * DD + 2 * c + keep_off]);
}

// Fallback (chunked path): build full Ain rows for one chunk.
__global__ __launch_bounds__(256)
void build_ain_kernel(const float* __restrict__ x, const float* __restrict__ cond,
                      unsigned short* __restrict__ Ain, int keep_off, int row0)
{
    int t = blockIdx.x * 256 + threadIdx.x;   // over CHv*128
    int c = t & 127, r = t >> 7;
    int grow = row0 + r;
    float v = 0.f;
    if (c < SPLIT)    v = x[(size_t)grow * DD + 2 * c + keep_off];
    else if (c < NIN) v = cond[(size_t)grow * CC + (c - SPLIT)];
    Ain[t] = f2bf(v);
}

// ---------------------------------------------------------------------------
// bf16 MFMA GEMM:  C = [relu](A @ B^T + bias)
// XCD-aware swizzle (N-block fastest within an XCD). __launch_bounds__(.,4)
// targets 4 waves/EU (4 blocks/CU); LDS capped at the 32 KB staging size via
// a two-pass epilogue (per-wave scratch = 32 rows).
// ---------------------------------------------------------------------------
template<int BM, int BN, int MT, int NT, int WM, int WN, bool OUT_BF16, bool RELU_BIAS>
__global__ __launch_bounds__(WM*WN*64, 4)
void mfma_gemm(const unsigned short* __restrict__ A,
               const unsigned short* __restrict__ Bt,
               const float* __restrict__ bias,
               void* __restrict__ Cc,
               int K, int N, int nbx)
{
    constexpr int WAVES = WM * WN;
    constexpr int AENT = 2 * (BM / 16);
    constexpr int BENT = 2 * (BN / 16);
    constexpr int STAGE_SH = (AENT + BENT) * 512;
    constexpr int EPI_STRIDE = 72;
    constexpr int EPI_SH = OUT_BF16 ? (WAVES * 32 * EPI_STRIDE) : 0;
    constexpr int LDS_SH = (EPI_SH > STAGE_SH) ? EPI_SH : STAGE_SH;
    __shared__ unsigned short lds[LDS_SH];

    const int t = threadIdx.x;
    const int w = t >> 6, lane = t & 63;
    const int lane16 = lane & 15, quad = lane >> 4;
    const int wm = w / WN, wn = w % WN;

    // ---- XCD swizzle ----
    int id = blockIdx.x;
    int nby = gridDim.x / nbx;
    int bx, by;
    if ((nby & 7) == 0) {
        int xcd = id & 7, slot = id >> 3;
        int q = slot / nbx;
        by = xcd * (nby >> 3) + q;
        bx = slot - q * nbx;
    } else { bx = id % nbx; by = id / nbx; }
    const int bm = by * BM, bn = bx * BN;

    unsigned short* ldsA = lds;
    unsigned short* ldsB = lds + AENT * 512;

    f32x4 acc[MT][NT];
#pragma unroll
    for (int a = 0; a < MT; ++a)
#pragma unroll
        for (int b = 0; b < NT; ++b) acc[a][b] = (f32x4){0.f, 0.f, 0.f, 0.f};

    for (int k0 = 0; k0 < K; k0 += 64) {
        for (int e = w; e < AENT; e += WAVES) {
            int s = e / (BM / 16), i = e % (BM / 16);
            const unsigned short* g = A + (size_t)(bm + i * 16 + lane16) * K + (k0 + s * 32 + quad * 8);
            __builtin_amdgcn_global_load_lds(
                (const __attribute__((address_space(1))) unsigned int*)g,
                (__attribute__((address_space(3))) unsigned int*)(ldsA + e * 512), 16, 0, 0);
        }
        for (int e = w; e < BENT; e += WAVES) {
            int s = e / (BN / 16), j = e % (BN / 16);
            const unsigned short* g = Bt + (size_t)(bn + j * 16 + lane16) * K + (k0 + s * 32 + quad * 8);
            __builtin_amdgcn_global_load_lds(
                (const __attribute__((address_space(1))) unsigned int*)g,
                (__attribute__((address_space(3))) unsigned int*)(ldsB + e * 512), 16, 0, 0);
        }
        __syncthreads();

#pragma unroll
        for (int s = 0; s < 2; ++s) {
            short8 af[MT], bfr[NT];
#pragma unroll
            for (int a = 0; a < MT; ++a)
                af[a] = *(const short8*)(ldsA + ((s * (BM / 16) + wm * MT + a) * 64 + lane) * 8);
#pragma unroll
            for (int b = 0; b < NT; ++b)
                bfr[b] = *(const short8*)(ldsB + ((s * (BN / 16) + wn * NT + b) * 64 + lane) * 8);
#pragma unroll
            for (int a = 0; a < MT; ++a)
#pragma unroll
                for (int b = 0; b < NT; ++b)
                    acc[a][b] = __builtin_amdgcn_mfma_f32_16x16x32_bf16(af[a], bfr[b], acc[a][b], 0, 0, 0);
        }
        __syncthreads();
    }

    // ---- epilogue ----
    if (OUT_BF16) {
        // two-pass (2 a-blocks per pass): per-wave scratch = 32 rows
        unsigned short* scr = lds + w * (32 * EPI_STRIDE);
        float bv[NT];
#pragma unroll
        for (int b = 0; b < NT; ++b)
            bv[b] = RELU_BIAS ? bias[bn + wn * NT * 16 + b * 16 + lane16] : 0.f;
        unsigned short* Co = (unsigned short*)Cc;
#pragma unroll
        for (int half = 0; half < MT / 2; ++half) {
#pragma unroll
            for (int a2 = 0; a2 < 2; ++a2) {
                int a = half * 2 + a2;
#pragma unroll
                for (int b = 0; b < NT; ++b)
#pragma unroll
                    for (int r = 0; r < 4; ++r) {
                        float v = acc[a][b][r] + bv[b];
                        if (RELU_BIAS) v = fmaxf(v, 0.f);
                        scr[(a2 * 16 + quad * 4 + r) * EPI_STRIDE + b * 16 + lane16] = f2bf(v);
                    }
            }
#pragma unroll
            for (int p = 0; p < 4; ++p) {   // 32 rows x 64 cols per pass (NT==4)
                int row = p * 8 + (lane >> 3);
                int colc = (lane & 7) * 8;
                short8 v = *(const short8*)(scr + row * EPI_STRIDE + colc);
                *(short8*)(Co + (size_t)(bm + wm * MT * 16 + half * 32 + row) * N
                                + bn + wn * NT * 16 + colc) = v;
            }
        }
    } else {
        float* Co = (float*)Cc;
#pragma unroll
        for (int a = 0; a < MT; ++a)
#pragma unroll
            for (int b = 0; b < NT; ++b)
#pragma unroll
                for (int r = 0; r < 4; ++r) {
                    int row = bm + wm * MT * 16 + a * 16 + quad * 4 + r;
                    int col = bn + wn * NT * 16 + b * 16 + lane16;
                    float v = acc[a][b][r];
                    if (RELU_BIAS) v = fmaxf(v + bias[col], 0.f);
                    Co[(size_t)row * N + col] = v;
                }
    }
}

// ---------------------------------------------------------------------------
// Fused GEMM3 + coupling. BM=64 (512 blocks -> ~2 blocks/CU), 4 waves (2x2),
// wave tile 32x32 (MT=NT=2). st tile in LDS (stride 66).
// ---------------------------------------------------------------------------
__global__ __launch_bounds__(256)
void gemm3_coupling(const unsigned short* __restrict__ A,   // h2 [CH][1024]
                    const unsigned short* __restrict__ Bt,  // wst [64][1024]
                    const float* __restrict__ bs, const float* __restrict__ bt,
                    float* __restrict__ x, float* __restrict__ log_det,
                    float* __restrict__ stat_sum, float* __restrict__ stat_sumsq,
                    int keep_off, int row0)
{
    constexpr int K = HH;
    constexpr int ST_STRIDE = 66;
    __shared__ float sst[64 * ST_STRIDE];             // 16.9 KB (aliased for staging)
    __shared__ float ssum[4][64], ssum2[4][64];
    unsigned short* lds = (unsigned short*)sst;

    const int t = threadIdx.x;
    const int w = t >> 6, lane = t & 63;
    const int lane16 = lane & 15, quad = lane >> 4;
    const int wm = w >> 1, wn = w & 1;
    const int bm = blockIdx.x * 64;

    unsigned short* ldsA = lds;              // 8 entries * 512
    unsigned short* ldsB = lds + 8 * 512;    // 8 entries * 512

    f32x4 acc[2][2];
#pragma unroll
    for (int a = 0; a < 2; ++a)
#pragma unroll
        for (int b = 0; b < 2; ++b) acc[a][b] = (f32x4){0.f, 0.f, 0.f, 0.f};

    for (int k0 = 0; k0 < K; k0 += 64) {
        for (int e = w; e < 8; e += 4) {
            int s = e >> 2, i = e & 3;
            const unsigned short* g = A + (size_t)(bm + i * 16 + lane16) * K + (k0 + s * 32 + quad * 8);
            __builtin_amdgcn_global_load_lds(
                (const __attribute__((address_space(1))) unsigned int*)g,
                (__attribute__((address_space(3))) unsigned int*)(ldsA + e * 512), 16, 0, 0);
        }
        for (int e = w; e < 8; e += 4) {
            int s = e >> 2, j = e & 3;
            const unsigned short* g = Bt + (size_t)(j * 16 + lane16) * K + (k0 + s * 32 + quad * 8);
            __builtin_amdgcn_global_load_lds(
                (const __attribute__((address_space(1))) unsigned int*)g,
                (__attribute__((address_space(3))) unsigned int*)(ldsB + e * 512), 16, 0, 0);
        }
        __syncthreads();
#pragma unroll
        for (int s = 0; s < 2; ++s) {
            short8 af[2], bfr[2];
#pragma unroll
            for (int a = 0; a < 2; ++a)
                af[a] = *(const short8*)(ldsA + ((s * 4 + wm * 2 + a) * 64 + lane) * 8);
#pragma unroll
            for (int b = 0; b < 2; ++b)
                bfr[b] = *(const short8*)(ldsB + ((s * 4 + wn * 2 + b) * 64 + lane) * 8);
#pragma unroll
            for (int a = 0; a < 2; ++a)
#pragma unroll
                for (int b = 0; b < 2; ++b)
                    acc[a][b] = __builtin_amdgcn_mfma_f32_16x16x32_bf16(af[a], bfr[b], acc[a][b], 0, 0, 0);
        }
        __syncthreads();
    }

    // scatter acc -> LDS st tile (64 rows x 64 cols)
#pragma unroll
    for (int a = 0; a < 2; ++a)
#pragma unroll
        for (int b = 0; b < 2; ++b)
#pragma unroll
            for (int r = 0; r < 4; ++r) {
                int row = wm * 32 + a * 16 + quad * 4 + r;
                int col = wn * 32 + b * 16 + lane16;
                sst[row * ST_STRIDE + col] = acc[a][b][r];
            }
    __syncthreads();

    // coupling: wave w -> rows [w*16, w*16+16), lane = feature f
    const int f = lane;
    const bool is_chg = ((f & 1) != keep_off);
    const int j = f >> 1;
    float bsj = 0.f, btj = 0.f;
    if (is_chg) { bsj = bs[j]; btj = bt[j]; }

    float lsum = 0.f, lsum2 = 0.f;
    for (int i = 0; i < 16; ++i) {
        int crow = w * 16 + i;
        int grow = row0 + bm + crow;
        float xv = x[(size_t)grow * DD + f];
        float ld = 0.f;
        if (is_chg) {
            float s_raw = sst[crow * ST_STRIDE + j];
            float t_raw = sst[crow * ST_STRIDE + SPLIT + j];
            float ls = tanhf(s_raw + bsj);
            float tv = t_raw + btj;
            xv = xv * expf(ls) + tv;
            x[(size_t)grow * DD + f] = xv;
            ld = ls;
        }
        for (int off = 32; off > 0; off >>= 1) ld += __shfl_down(ld, off, 64);
        if (f == 0) log_det[grow] += ld;
        lsum  += xv;
        lsum2 += xv * xv;
    }

    ssum[w][f]  = lsum;
    ssum2[w][f] = lsum2;
    __syncthreads();
    if (t < 64) {
        float a = ssum[0][t] + ssum[1][t] + ssum[2][t] + ssum[3][t];
        float b = ssum2[0][t] + ssum2[1][t] + ssum2[2][t] + ssum2[3][t];
        atomicAdd(stat_sum + t, a);
        atomicAdd(stat_sumsq + t, b);
    }
}

// ---------------------------------------------------------------------------
__global__ void finalize_kernel(const float* __restrict__ stat_sum, const float* __restrict__ stat_sumsq,
                                const float* __restrict__ bn_w, const float* __restrict__ bn_b,
                                float* __restrict__ scale, float* __restrict__ shift,
                                float* __restrict__ cbuf)
{
    int f = threadIdx.x;  // 64
    const float invB = 1.f / (float)BB;
    float mean = stat_sum[f] * invB;
    float var  = stat_sumsq[f] * invB - mean * mean;
    float inv  = rsqrtf(var + EPSV);
    float w    = bn_w[f];
    float sc   = inv * w;
    scale[f] = sc;
    shift[f] = bn_b[f] - mean * sc;
    float lg = logf(fabsf(w));
    for (int off = 32; off > 0; off >>= 1) lg += __shfl_down(lg, off, 64);
    if (f == 0) cbuf[0] = lg;
}

// ---------------------------------------------------------------------------
// BN normalize; optionally also writes bf16 keep-columns of next layer's Ain.
// ---------------------------------------------------------------------------
__global__ __launch_bounds__(256)
void normalize_kernel(const float* __restrict__ xin, float* __restrict__ xout,
                      const float* __restrict__ scale, const float* __restrict__ shift,
                      const float* __restrict__ cbuf, float* __restrict__ log_det,
                      unsigned short* __restrict__ Ain, int off_next)
{
    int idx = blockIdx.x * blockDim.x + threadIdx.x;     // over B*64/4
    int f0 = (idx & 15) * 4;
    int row = idx >> 4;
    float4 v = ((const float4*)xin)[idx];
    v.x = v.x * scale[f0 + 0] + shift[f0 + 0];
    v.y = v.y * scale[f0 + 1] + shift[f0 + 1];
    v.z = v.z * scale[f0 + 2] + shift[f0 + 2];
    v.w = v.w * scale[f0 + 3] + shift[f0 + 3];
    ((float4*)xout)[idx] = v;
    if ((idx & 15) == 0) log_det[row] += cbuf[0];
    if (Ain) {
        float a0 = off_next ? v.y : v.x;
        float a1 = off_next ? v.w : v.z;
        ushort2 u; u.x = f2bf(a0); u.y = f2bf(a1);
        *(ushort2*)(Ain + (size_t)row * 128 + (f0 >> 1)) = u;
    }
}

// ---------------------------------------------------------------------------
extern "C" void kernel_launch(void* const* d_in, const int* in_sizes, int n_in,
                              void* d_out, int out_size, void* d_ws, size_t ws_size,
                              hipStream_t stream)
{
    const float* z    = (const float*)d_in[0];
    const float* cond = (const float*)d_in[1];
    const float* W1   = (const float*)d_in[2];
    const float* b1   = (const float*)d_in[3];
    const float* W2   = (const float*)d_in[4];
    const float* b2   = (const float*)d_in[5];
    const float* Ws   = (const float*)d_in[6];
    const float* bs   = (const float*)d_in[7];
    const float* Wt   = (const float*)d_in[8];
    const float* bt   = (const float*)d_in[9];
    const float* bn_w = (const float*)d_in[10];
    const float* bn_b = (const float*)d_in[11];

    float* out_x  = (float*)d_out;
    float* out_ld = out_x + (size_t)BB * DD;

    // ---- workspace layout ----
    char* p = (char*)d_ws;
    size_t used = 0;
    auto alloc = [&](size_t bytes) { void* q = p + used; used += (bytes + 255) & ~(size_t)255; return q; };

    float*          xbuf = (float*)alloc((size_t)BB * DD * 4);
    unsigned short* w1t  = (unsigned short*)alloc((size_t)LL * HH * 128 * 2);
    unsigned short* w2t  = (unsigned short*)alloc((size_t)LL * HH * HH * 2);
    unsigned short* wstt = (unsigned short*)alloc((size_t)LL * 64 * HH * 2);
    float* stat_sum   = (float*)alloc(64 * 4);
    float* stat_sumsq = (float*)alloc(64 * 4);
    float* scalev     = (float*)alloc(64 * 4);
    float* shiftv     = (float*)alloc(64 * 4);
    float* cbuf       = (float*)alloc(64 * 4);

    // per-chunk bytes: Ain 256 + h1 2048 + h2 2048 = 4352 B/row
    int CHv = BB;
    while (CHv > 8192 && used + (size_t)CHv * 4352 + 4096 > ws_size) CHv >>= 1;
    const bool fused = (CHv == BB);

    unsigned short* Ain = (unsigned short*)alloc((size_t)CHv * 128 * 2);
    unsigned short* h1  = (unsigned short*)alloc((size_t)CHv * HH * 2);
    unsigned short* h2  = (unsigned short*)alloc((size_t)CHv * HH * 2);

    // ---- init ----
    hipMemcpyAsync(xbuf, z, (size_t)BB * DD * sizeof(float), hipMemcpyDeviceToDevice, stream);
    hipMemsetAsync(out_ld, 0, (size_t)BB * sizeof(float), stream);

    transpose_cvt_kernel<<<dim3(128/32, HH/32, LL), 256, 0, stream>>>(
        W1, w1t, NIN, HH, 128, (long long)NIN * HH, (long long)HH * 128);
    transpose_cvt_kernel<<<dim3(HH/32, HH/32, LL), 256, 0, stream>>>(
        W2, w2t, HH, HH, HH, (long long)HH * HH, (long long)HH * HH);
    transpose_cvt_kernel<<<dim3(HH/32, SPLIT/32, LL), 256, 0, stream>>>(
        Ws, wstt, HH, SPLIT, HH, (long long)HH * SPLIT, (long long)64 * HH);
    transpose_cvt_kernel<<<dim3(HH/32, SPLIT/32, LL), 256, 0, stream>>>(
        Wt, wstt + (size_t)SPLIT * HH, HH, SPLIT, HH, (long long)HH * SPLIT, (long long)64 * HH);

    if (fused) {
        init_ain_cond_kernel<<<BB * 96 / 256, 256, 0, stream>>>(cond, Ain);
        build_keep_kernel<<<BB * 32 / 256, 256, 0, stream>>>(xbuf, Ain, 0);
    }

    for (int l = 0; l < LL; ++l) {
        const int off = l & 1;
        hipMemsetAsync(stat_sum, 0, 2 * 64 * sizeof(float), stream);

        for (int c = 0; c < BB / CHv; ++c) {
            const int row0 = c * CHv;

            if (!fused)
                build_ain_kernel<<<CHv * 128 / 256, 256, 0, stream>>>(xbuf, cond, Ain, off, row0);

            // GEMM1: h1 = relu(Ain @ W1t^T + b1)   M=CHv, K=128(pad), N=1024
            mfma_gemm<128,128,4,4,2,2,true,true><<<(HH/128) * (CHv/128), 256, 0, stream>>>(
                Ain, w1t + (size_t)l * HH * 128, b1 + (size_t)l * HH, h1, 128, HH, HH/128);

            // GEMM2: h2 = relu(h1 @ W2t^T + b2)    M=CHv, K=1024, N=1024
            mfma_gemm<128,128,4,4,2,2,true,true><<<(HH/128) * (CHv/128), 256, 0, stream>>>(
                h1, w2t + (size_t)l * HH * HH, b2 + (size_t)l * HH, h2, HH, HH, HH/128);

            // GEMM3 + coupling fused (BM=64)
            gemm3_coupling<<<CHv/64, 256, 0, stream>>>(
                h2, wstt + (size_t)l * 64 * HH,
                bs + (size_t)l * SPLIT, bt + (size_t)l * SPLIT,
                xbuf, out_ld, stat_sum, stat_sumsq, off, row0);
        }

        finalize_kernel<<<1, 64, 0, stream>>>(
            stat_sum, stat_sumsq, bn_w + (size_t)l * DD, bn_b + (size_t)l * DD,
            scalev, shiftv, cbuf);

        float* xout = (l == LL - 1) ? out_x : xbuf;
        unsigned short* ain_next = (fused && l < LL - 1) ? Ain : nullptr;
        normalize_kernel<<<(BB * DD / 4) / 256, 256, 0, stream>>>(
            xbuf, xout, scalev, shiftv, cbuf, out_ld, ain_next, (l + 1) & 1);
    }
}